// Round 5
// baseline (105.661 us; speedup 1.0000x reference)
//
#include <hip/hip_runtime.h>
#include <math.h>

#define F_    16
#define NV_   4096
#define NT_   512
#define M_    4096
#define PPF_  (NV_ + NT_)        // 4608 points per frame
#define NPTS_ (F_ * PPF_)        // 73728 total points
#define SCALE_INV 10.0f          // 1 / 0.1

#define TPB   256
#define PTSB  72                 // 64 blocks/frame (no straddle); 1024 blocks = 4/CU exact
#define NBLK  (NPTS_ / PTSB)     // 1024
#define NG    32                 // model groups (8 per wave: g = t>>3)
#define MPG   (M_ / NG)          // 128 models per group
#define CHM   32                 // models per group per chunk
#define NCH   (MPG / CHM)        // 4 chunks
#define FS    33                 // float4 stride/group: (g*33+m)&7 = (g+m)&7 -> 8 disjoint bank-quads/wave
#define PPL   9                  // points per lane (8 point-lanes x 9 = 72)

// ---------------------------------------------------------------- pose math
__device__ inline void rot_from_omega(float ox, float oy, float oz, float dt,
                                      float* R) {
    // R = I + sin(theta*dt)*S + (1-cos(theta*dt))*S^2,  S = skew(omega/max(theta,1e-8))
    float theta = sqrtf(ox * ox + oy * oy + oz * oz);
    float inv = 1.0f / fmaxf(theta, 1e-8f);
    float ax = ox * inv, ay = oy * inv, az = oz * inv;
    float s = sinf(theta * dt);
    float c = 1.0f - cosf(theta * dt);
    R[0] = 1.0f - c * (ay * ay + az * az);
    R[1] = -s * az + c * ax * ay;
    R[2] =  s * ay + c * ax * az;
    R[3] =  s * az + c * ax * ay;
    R[4] = 1.0f - c * (ax * ax + az * az);
    R[5] = -s * ax + c * ay * az;
    R[6] = -s * ay + c * ax * az;
    R[7] =  s * ax + c * ay * az;
    R[8] = 1.0f - c * (ax * ax + ay * ay);
}

// ---------------------------------------------------------------- fused kernel
// Resubmission of round-4 (bench died on container acquisition, not kernel
// evidence). Theory under test: round-3's ~38us kernel was VGPR-spill +
// thin occupancy. This version: 1024 blocks = 4/CU (4 waves/SIMD), PPL=9 +
// unroll 4 under a 128-reg cap (no spill), pose chain computed per-thread
// (block-uniform -> no divergence, no serial 1-lane phase, no pose LDS or
// extra barriers), points transformed straight into registers.
__global__ __launch_bounds__(TPB, 4) void chamfer_one(
    const float* __restrict__ state, const float* __restrict__ model,
    const float* __restrict__ vis, const float* __restrict__ tac,
    const float* __restrict__ phys, const float* __restrict__ dts,
    float* __restrict__ out) {
    __shared__ float4 feat[NG * FS];        // 16.9 KB model features {-2g, |g|^2}
    __shared__ float  sdm[PTSB][NG + 1];    // 9.5 KB per-point per-group mins (+1 pad)
    __shared__ float  sw[2];

    const int t  = threadIdx.x;
    const int g  = t >> 3;                  // model group 0..31
    const int m0 = t & 7;
    const int pl = t & 7;                   // point-lane 0..7 (9 points each)
    const int f  = (blockIdx.x * PTSB) / PPF_;          // block-uniform
    const int lbase = blockIdx.x * PTSB - f * PPF_;

    // ---- stage chunk 0 early (hide under pose math) ----
#pragma unroll
    for (int j2 = 0; j2 < 4; ++j2) {
        int id = g * MPG + m0 + 8 * j2;
        float gx = model[id * 3 + 0], gy = model[id * 3 + 1], gz = model[id * 3 + 2];
        feat[g * FS + m0 + 8 * j2] =
            make_float4(-2.0f * gx, -2.0f * gy, -2.0f * gz, gx * gx + gy * gy + gz * gz);
    }

    // ---- pose for frame f, computed by every thread (uniform f -> no divergence;
    // identical op order to the reference scan -> bit-identical result) ----
    float R[9], tr[3];
    {
        tr[0] = state[0]; tr[1] = state[1]; tr[2] = state[2];
        rot_from_omega(state[3], state[4], state[5], 1.0f, R);
        for (int i = 1; i <= f; ++i) {
            float dt = dts[i];
            tr[0] += phys[i * 12 + 6] * dt;
            tr[1] += phys[i * 12 + 7] * dt;
            tr[2] += phys[i * 12 + 8] * dt;
            float Rs[9];
            rot_from_omega(phys[i * 12 + 9], phys[i * 12 + 10], phys[i * 12 + 11], dt, Rs);
            float Rn[9];
            for (int r = 0; r < 3; ++r)
                for (int c2 = 0; c2 < 3; ++c2)
                    Rn[r * 3 + c2] = Rs[r * 3 + 0] * R[0 + c2] +
                                     Rs[r * 3 + 1] * R[3 + c2] +
                                     Rs[r * 3 + 2] * R[6 + c2];
            for (int j = 0; j < 9; ++j) R[j] = Rn[j];
        }
        for (int j = 0; j < 9; ++j) R[j] *= SCALE_INV;  // fold 1/SCALE
    }

    // ---- transform my 9 points into registers: c = (p - t) @ (R/SCALE) ----
    // (32 threads share each pl -> redundant loads hit L1/L2; no LDS round-trip)
    float c0[PPL], c1[PPL], c2[PPL], cn[PPL], dm[PPL];
#pragma unroll
    for (int k = 0; k < PPL; ++k) {
        int loc = lbase + pl * PPL + k;
        const float* p = (loc < NV_) ? (vis + ((size_t)f * NV_ + loc) * 3)
                                     : (tac + ((size_t)f * NT_ + (loc - NV_)) * 3);
        float d0 = p[0] - tr[0], d1 = p[1] - tr[1], d2 = p[2] - tr[2];
        float x = d0 * R[0] + d1 * R[3] + d2 * R[6];
        float y = d0 * R[1] + d1 * R[4] + d2 * R[7];
        float z = d0 * R[2] + d1 * R[5] + d2 * R[8];
        c0[k] = x; c1[k] = y; c2[k] = z;
        cn[k] = x * x + y * y + z * z;
        dm[k] = 3.4e38f;
    }
    __syncthreads();

    // ---- main loop: 4 chunks x 32 models/group; single LDS buffer,
    // next chunk prefetched into registers before compute (T14 split) ----
    for (int c = 0; c < NCH; ++c) {
        float mx[4], my[4], mz[4];
        if (c + 1 < NCH) {
#pragma unroll
            for (int j2 = 0; j2 < 4; ++j2) {
                int id = g * MPG + (c + 1) * CHM + m0 + 8 * j2;
                mx[j2] = model[id * 3 + 0];
                my[j2] = model[id * 3 + 1];
                mz[j2] = model[id * 3 + 2];
            }
        }
        const float4* fb = &feat[g * FS];
#pragma unroll 4
        for (int m = 0; m < CHM; m += 2) {
            float4 ga = fb[m];       // 8 distinct addrs/wave on 8 disjoint quads
            float4 gb = fb[m + 1];   // broadcast to 8 lanes each: conflict-free
#pragma unroll
            for (int k = 0; k < PPL; ++k) {
                float da = fmaf(ga.x, c0[k], fmaf(ga.y, c1[k], fmaf(ga.z, c2[k], ga.w)));
                float db = fmaf(gb.x, c0[k], fmaf(gb.y, c1[k], fmaf(gb.z, c2[k], gb.w)));
                dm[k] = fminf(fminf(da, db), dm[k]);   // -> v_min3_f32
            }
        }
        __syncthreads();             // all reads of chunk c done
        if (c + 1 < NCH) {
#pragma unroll
            for (int j2 = 0; j2 < 4; ++j2) {
                feat[g * FS + m0 + 8 * j2] =
                    make_float4(-2.0f * mx[j2], -2.0f * my[j2], -2.0f * mz[j2],
                                mx[j2] * mx[j2] + my[j2] * my[j2] + mz[j2] * mz[j2]);
            }
            __syncthreads();         // chunk c+1 staged
        }
    }

    // ---- combine 32 group-partials per point, weight, block-sum, one atomic ----
#pragma unroll
    for (int k = 0; k < PPL; ++k) sdm[pl * PPL + k][g] = dm[k] + cn[k];
    __syncthreads();

    float v = 0.0f;
    if (t < PTSB) {
        const float* row = sdm[t];
        float mn = row[0];
#pragma unroll
        for (int i = 1; i < NG; ++i) mn = fminf(mn, row[i]);
        const int loc = lbase + t;
        const float w = (loc < NV_) ? (1.0f / NV_) : (0.1f / NT_);
        v = mn * w;
    }
    if (t < 128) {
#pragma unroll
        for (int off = 32; off > 0; off >>= 1) v += __shfl_down(v, off);
        if ((t & 63) == 0) sw[t >> 6] = v;
    }
    __syncthreads();
    if (t == 0) atomicAdd(out, sw[0] + sw[1]);
}

// ---------------------------------------------------------------- launch
// d_ws unused: the 256MB ws poison fill (~40us) runs unconditionally
// (rounds 1-3 evidence), so workspace buys nothing; single fused kernel.
extern "C" void kernel_launch(void* const* d_in, const int* in_sizes, int n_in,
                              void* d_out, int out_size, void* d_ws, size_t ws_size,
                              hipStream_t stream) {
    const float* state = (const float*)d_in[0];   // (6,)
    const float* model = (const float*)d_in[1];   // (M,3)
    const float* vis   = (const float*)d_in[2];   // (F,NV,3)
    const float* tac   = (const float*)d_in[3];   // (F,NT,3)
    const float* phys  = (const float*)d_in[4];   // (F,12)
    const float* dts   = (const float*)d_in[5];   // (F,)
    float* out = (float*)d_out;
    (void)d_ws; (void)ws_size;

    hipMemsetAsync(out, 0, sizeof(float), stream);
    chamfer_one<<<NBLK, TPB, 0, stream>>>(state, model, vis, tac, phys, dts, out);
}

// Round 6
// 98.780 us; speedup vs baseline: 1.0697x; 1.0697x over previous
//
#include <hip/hip_runtime.h>
#include <math.h>

#define F_    16
#define NV_   4096
#define NT_   512
#define M_    4096
#define PPF_  (NV_ + NT_)        // 4608 points per frame
#define NPTS_ (F_ * PPF_)        // 73728 total points
#define SCALE_INV 10.0f          // 1 / 0.1

#define TPB   256
#define PTSB  64                 // 72 blocks/frame (no straddle); 1152 blocks
#define NBLK  (NPTS_ / PTSB)     // 1152
#define NG    32                 // model groups (8 per wave: g = t>>3)
#define MPG   (M_ / NG)          // 128 models per group
#define CHM   32                 // models per group per chunk
#define NCH   (MPG / CHM)        // 4 chunks
#define FS    33                 // v4 stride/group: quad(g,m) = (g+m)&7 -> 8 disjoint bank-quads/wave
#define PPL   8                  // points per lane (8 lanes x 8 = 64), even for f32 pairing

typedef float v2f __attribute__((ext_vector_type(2)));
typedef float v4f __attribute__((ext_vector_type(4)));

// ---------------------------------------------------------------- pose math
__device__ inline void rot_from_omega(float ox, float oy, float oz, float dt,
                                      float* R) {
    // R = I + sin(theta*dt)*S + (1-cos(theta*dt))*S^2,  S = skew(omega/max(theta,1e-8))
    float theta = sqrtf(ox * ox + oy * oy + oz * oz);
    float inv = 1.0f / fmaxf(theta, 1e-8f);
    float ax = ox * inv, ay = oy * inv, az = oz * inv;
    float s = sinf(theta * dt);
    float c = 1.0f - cosf(theta * dt);
    R[0] = 1.0f - c * (ay * ay + az * az);
    R[1] = -s * az + c * ax * ay;
    R[2] =  s * ay + c * ax * az;
    R[3] =  s * az + c * ax * ay;
    R[4] = 1.0f - c * (ax * ax + az * az);
    R[5] = -s * ax + c * ay * az;
    R[6] = -s * ay + c * ax * az;
    R[7] =  s * ax + c * ay * az;
    R[8] = 1.0f - c * (ax * ax + ay * ay);
}

// ---------------------------------------------------------------- fused kernel
// Round-5 evidence: VALU-issue-bound (VALUBusy 76%, no spill, no conflicts,
// no memory). Fix: halve+ the instruction stream with packed f32 math.
// Inner step (2 models x 4 point-pairs) is one asm block of 24 v_pk_fma_f32;
// op_sel broadcasts the model scalars straight out of the ds_read_b128 quad
// ({-2gx,-2gy} pair serves gx and gy; {-2gz,w} serves gz and the addend w),
// so no per-model unpack moves. pk_fma == IEEE fma f32: bit-identical math.
__global__ __launch_bounds__(TPB, 4) void chamfer_one(
    const float* __restrict__ state, const float* __restrict__ model,
    const float* __restrict__ vis, const float* __restrict__ tac,
    const float* __restrict__ phys, const float* __restrict__ dts,
    float* __restrict__ out) {
    __shared__ v4f   feat[NG * FS];         // 16.9 KB model features {-2g, |g|^2}
    __shared__ float sdm[PTSB][NG + 1];     // 8.4 KB per-point per-group mins (+1 pad)

    const int t  = threadIdx.x;
    const int g  = t >> 3;                  // model group 0..31
    const int m0 = t & 7;
    const int pl = t & 7;                   // point-lane 0..7 (8 points each)
    const int f  = (blockIdx.x * PTSB) / PPF_;          // block-uniform
    const int lbase = blockIdx.x * PTSB - f * PPF_;

    // ---- stage chunk 0 early (hide under pose math) ----
#pragma unroll
    for (int j2 = 0; j2 < 4; ++j2) {
        int id = g * MPG + m0 + 8 * j2;
        float gx = model[id * 3 + 0], gy = model[id * 3 + 1], gz = model[id * 3 + 2];
        feat[g * FS + m0 + 8 * j2] =
            (v4f){-2.0f * gx, -2.0f * gy, -2.0f * gz, gx * gx + gy * gy + gz * gz};
    }

    // ---- pose for frame f, computed per-thread (uniform f -> no divergence;
    // identical op order to the reference scan) ----
    float R[9], tr[3];
    {
        tr[0] = state[0]; tr[1] = state[1]; tr[2] = state[2];
        rot_from_omega(state[3], state[4], state[5], 1.0f, R);
        for (int i = 1; i <= f; ++i) {
            float dt = dts[i];
            tr[0] += phys[i * 12 + 6] * dt;
            tr[1] += phys[i * 12 + 7] * dt;
            tr[2] += phys[i * 12 + 8] * dt;
            float Rs[9];
            rot_from_omega(phys[i * 12 + 9], phys[i * 12 + 10], phys[i * 12 + 11], dt, Rs);
            float Rn[9];
            for (int r = 0; r < 3; ++r)
                for (int c2 = 0; c2 < 3; ++c2)
                    Rn[r * 3 + c2] = Rs[r * 3 + 0] * R[0 + c2] +
                                     Rs[r * 3 + 1] * R[3 + c2] +
                                     Rs[r * 3 + 2] * R[6 + c2];
            for (int j = 0; j < 9; ++j) R[j] = Rn[j];
        }
        for (int j = 0; j < 9; ++j) R[j] *= SCALE_INV;  // fold 1/SCALE
    }

    // ---- transform my 8 points; pack coords as f32 pairs for pk math ----
    v2f c0p[4], c1p[4], c2p[4];
    float cn[PPL], dm[PPL];
    {
        float xx[PPL], yy[PPL], zz[PPL];
#pragma unroll
        for (int k = 0; k < PPL; ++k) {
            int loc = lbase + pl * PPL + k;
            const float* p = (loc < NV_) ? (vis + ((size_t)f * NV_ + loc) * 3)
                                         : (tac + ((size_t)f * NT_ + (loc - NV_)) * 3);
            float d0 = p[0] - tr[0], d1 = p[1] - tr[1], d2 = p[2] - tr[2];
            float x = d0 * R[0] + d1 * R[3] + d2 * R[6];
            float y = d0 * R[1] + d1 * R[4] + d2 * R[7];
            float z = d0 * R[2] + d1 * R[5] + d2 * R[8];
            xx[k] = x; yy[k] = y; zz[k] = z;
            cn[k] = x * x + y * y + z * z;
            dm[k] = 3.4e38f;
        }
#pragma unroll
        for (int j = 0; j < 4; ++j) {
            c0p[j] = (v2f){xx[2 * j], xx[2 * j + 1]};
            c1p[j] = (v2f){yy[2 * j], yy[2 * j + 1]};
            c2p[j] = (v2f){zz[2 * j], zz[2 * j + 1]};
        }
    }
    __syncthreads();

    // ---- main loop: 4 chunks x 32 models/group; reg-prefetch next chunk ----
    for (int c = 0; c < NCH; ++c) {
        float mx[4], my[4], mz[4];
        if (c + 1 < NCH) {
#pragma unroll
            for (int j2 = 0; j2 < 4; ++j2) {
                int id = g * MPG + (c + 1) * CHM + m0 + 8 * j2;
                mx[j2] = model[id * 3 + 0];
                my[j2] = model[id * 3 + 1];
                mz[j2] = model[id * 3 + 2];
            }
        }
        const v4f* fb = &feat[g * FS];
#pragma unroll 2
        for (int m = 0; m < CHM; m += 2) {
            v4f ga = fb[m];          // {-2gx,-2gy,-2gz,w}: 8 addrs/wave, disjoint quads
            v4f gb = fb[m + 1];
            v2f qA01 = __builtin_shufflevector(ga, ga, 0, 1);  // {-2gx,-2gy}
            v2f qA23 = __builtin_shufflevector(ga, ga, 2, 3);  // {-2gz,  w}
            v2f qB01 = __builtin_shufflevector(gb, gb, 0, 1);
            v2f qB23 = __builtin_shufflevector(gb, gb, 2, 3);
            v2f A0, A1, A2, A3, B0, B1, B2, B3;
            // Dj = fma(gx, c0p[j], fma(gy, c1p[j], fma(gz, c2p[j], w))) for 2 pts
            // op_sel broadcasts: src word0 both halves -> op_sel 0 / op_sel_hi 0;
            // word1 both halves -> 1/1; packed operand natural -> 0/1.
            asm("v_pk_fma_f32 %0, %9, %20, %9  op_sel:[0,0,1] op_sel_hi:[0,1,1]\n\t"
                "v_pk_fma_f32 %4, %11, %20, %11 op_sel:[0,0,1] op_sel_hi:[0,1,1]\n\t"
                "v_pk_fma_f32 %1, %9, %21, %9  op_sel:[0,0,1] op_sel_hi:[0,1,1]\n\t"
                "v_pk_fma_f32 %5, %11, %21, %11 op_sel:[0,0,1] op_sel_hi:[0,1,1]\n\t"
                "v_pk_fma_f32 %2, %9, %22, %9  op_sel:[0,0,1] op_sel_hi:[0,1,1]\n\t"
                "v_pk_fma_f32 %6, %11, %22, %11 op_sel:[0,0,1] op_sel_hi:[0,1,1]\n\t"
                "v_pk_fma_f32 %3, %9, %23, %9  op_sel:[0,0,1] op_sel_hi:[0,1,1]\n\t"
                "v_pk_fma_f32 %7, %11, %23, %11 op_sel:[0,0,1] op_sel_hi:[0,1,1]\n\t"
                "v_pk_fma_f32 %0, %8, %16, %0  op_sel:[1,0,0] op_sel_hi:[1,1,1]\n\t"
                "v_pk_fma_f32 %4, %10, %16, %4 op_sel:[1,0,0] op_sel_hi:[1,1,1]\n\t"
                "v_pk_fma_f32 %1, %8, %17, %1  op_sel:[1,0,0] op_sel_hi:[1,1,1]\n\t"
                "v_pk_fma_f32 %5, %10, %17, %5 op_sel:[1,0,0] op_sel_hi:[1,1,1]\n\t"
                "v_pk_fma_f32 %2, %8, %18, %2  op_sel:[1,0,0] op_sel_hi:[1,1,1]\n\t"
                "v_pk_fma_f32 %6, %10, %18, %6 op_sel:[1,0,0] op_sel_hi:[1,1,1]\n\t"
                "v_pk_fma_f32 %3, %8, %19, %3  op_sel:[1,0,0] op_sel_hi:[1,1,1]\n\t"
                "v_pk_fma_f32 %7, %10, %19, %7 op_sel:[1,0,0] op_sel_hi:[1,1,1]\n\t"
                "v_pk_fma_f32 %0, %8, %12, %0  op_sel:[0,0,0] op_sel_hi:[0,1,1]\n\t"
                "v_pk_fma_f32 %4, %10, %12, %4 op_sel:[0,0,0] op_sel_hi:[0,1,1]\n\t"
                "v_pk_fma_f32 %1, %8, %13, %1  op_sel:[0,0,0] op_sel_hi:[0,1,1]\n\t"
                "v_pk_fma_f32 %5, %10, %13, %5 op_sel:[0,0,0] op_sel_hi:[0,1,1]\n\t"
                "v_pk_fma_f32 %2, %8, %14, %2  op_sel:[0,0,0] op_sel_hi:[0,1,1]\n\t"
                "v_pk_fma_f32 %6, %10, %14, %6 op_sel:[0,0,0] op_sel_hi:[0,1,1]\n\t"
                "v_pk_fma_f32 %3, %8, %15, %3  op_sel:[0,0,0] op_sel_hi:[0,1,1]\n\t"
                "v_pk_fma_f32 %7, %10, %15, %7 op_sel:[0,0,0] op_sel_hi:[0,1,1]"
                : "=&v"(A0), "=&v"(A1), "=&v"(A2), "=&v"(A3),
                  "=&v"(B0), "=&v"(B1), "=&v"(B2), "=&v"(B3)
                : "v"(qA01), "v"(qA23), "v"(qB01), "v"(qB23),
                  "v"(c0p[0]), "v"(c0p[1]), "v"(c0p[2]), "v"(c0p[3]),
                  "v"(c1p[0]), "v"(c1p[1]), "v"(c1p[2]), "v"(c1p[3]),
                  "v"(c2p[0]), "v"(c2p[1]), "v"(c2p[2]), "v"(c2p[3]));
            // 8 v_min3 fold both models into the per-point running mins
            dm[0] = fminf(fminf(A0.x, B0.x), dm[0]);
            dm[1] = fminf(fminf(A0.y, B0.y), dm[1]);
            dm[2] = fminf(fminf(A1.x, B1.x), dm[2]);
            dm[3] = fminf(fminf(A1.y, B1.y), dm[3]);
            dm[4] = fminf(fminf(A2.x, B2.x), dm[4]);
            dm[5] = fminf(fminf(A2.y, B2.y), dm[5]);
            dm[6] = fminf(fminf(A3.x, B3.x), dm[6]);
            dm[7] = fminf(fminf(A3.y, B3.y), dm[7]);
        }
        __syncthreads();             // all reads of chunk c done
        if (c + 1 < NCH) {
#pragma unroll
            for (int j2 = 0; j2 < 4; ++j2) {
                feat[g * FS + m0 + 8 * j2] =
                    (v4f){-2.0f * mx[j2], -2.0f * my[j2], -2.0f * mz[j2],
                          mx[j2] * mx[j2] + my[j2] * my[j2] + mz[j2] * mz[j2]};
            }
            __syncthreads();         // chunk c+1 staged
        }
    }

    // ---- combine 32 group-partials per point, weight, wave-0 sum, one atomic ----
#pragma unroll
    for (int k = 0; k < PPL; ++k) sdm[pl * PPL + k][g] = dm[k] + cn[k];
    __syncthreads();

    if (t < PTSB) {                  // exactly wave 0
        const float* row = sdm[t];
        float mn = row[0];
#pragma unroll
        for (int i = 1; i < NG; ++i) mn = fminf(mn, row[i]);
        const int loc = lbase + t;
        const float w = (loc < NV_) ? (1.0f / NV_) : (0.1f / NT_);
        float v = mn * w;
#pragma unroll
        for (int off = 32; off > 0; off >>= 1) v += __shfl_down(v, off);
        if (t == 0) atomicAdd(out, v);
    }
}

// ---------------------------------------------------------------- launch
// d_ws unused: the 256MB ws poison fill (~40us) runs unconditionally
// (rounds 1-5 evidence), so workspace buys nothing; single fused kernel.
extern "C" void kernel_launch(void* const* d_in, const int* in_sizes, int n_in,
                              void* d_out, int out_size, void* d_ws, size_t ws_size,
                              hipStream_t stream) {
    const float* state = (const float*)d_in[0];   // (6,)
    const float* model = (const float*)d_in[1];   // (M,3)
    const float* vis   = (const float*)d_in[2];   // (F,NV,3)
    const float* tac   = (const float*)d_in[3];   // (F,NT,3)
    const float* phys  = (const float*)d_in[4];   // (F,12)
    const float* dts   = (const float*)d_in[5];   // (F,)
    float* out = (float*)d_out;
    (void)d_ws; (void)ws_size;

    hipMemsetAsync(out, 0, sizeof(float), stream);
    chamfer_one<<<NBLK, TPB, 0, stream>>>(state, model, vis, tac, phys, dts, out);
}